// Round 1
// 511.474 us; speedup vs baseline: 1.6163x; 1.6163x over previous
//
#include <hip/hip_runtime.h>
#include <hip/hip_bf16.h>

// ---------------------------------------------------------------------------
// MultiHeadAttention_24893630447703  (B=2, S=2048, D=1024, H=16, DH=64)
//
// Inherited (harness-verified) algebra: post-softmax -1e9 causal fill
// dominates the output:
//   out[b,128h+t,n] = bo[n] - 1e9 * ( sum_{r>t} G[b,128h+r,n] + u[b,128h+t,n] )
// with
//   Wcum[64q+dh,n] = sum_{q'<q} Wo[64q'+dh,n] ; WoSum[dh,n] = sum_q Wo[64q+dh,n]
//   Wvc = Wv @ Wcum ; bvc = bv @ Wcum ; u = V @ Wvc + bvc
//   WvFold[k,dh] = sum_q Wv[k,64q+dh]  ; bvFold[dh] = sum_q bv[64q+dh]
//   G = (V @ WvFold + bvFold) @ WoSum  = V @ W2 + b2,
//        W2 = WvFold @ WoSum  [1024x1024], b2 = bvFold @ WoSum
//
// This revision (fp32 throughput rewrite):
//  * one FMA-bound 128x128/BK16 8x8-microtile GEMM kernel (ds_read_b128,
//    conflict-free LDS, XCD swizzle, optional split-K atomics)
//  * big GEMM fused: ubig = V @ [Wvc | W2] + [bvc | b2], N=2048 ->
//    grid 16x32 = 512 blocks = exactly 2 blocks/CU, fully co-resident
//  * epilogue = pure memory-bound suffix scan (u and G adjacent in ubig)
//  * parallel dtype detector; split-D bvc; split-K Wvc
// ---------------------------------------------------------------------------

typedef __hip_bfloat16 bf16;
typedef __attribute__((ext_vector_type(8))) unsigned short ushort8;

// workspace layout (float offsets) -- total ~44.5 MiB
constexpr size_t OFF_WCUM  = 0;                         // 1024*1024
constexpr size_t OFF_WBIG  = 1048576;                   // 1024*2048  [Wvc | W2]
constexpr size_t OFF_UBIG  = 3145728;                   // 4096*2048  [u | G]
constexpr size_t OFF_WOSUM = 11534336;                  // 64*1024
constexpr size_t OFF_WVF   = 11599872;                  // 1024*64
constexpr size_t OFF_BBIG  = 11665408;                  // 2048       [bvc | b2]
constexpr size_t OFF_BVF   = 11667456;                  // 64
constexpr size_t OFF_FLAG  = 11667520;                  // 1 int

__device__ __forceinline__ float toF(bf16 x)  { return __bfloat162float(x); }
__device__ __forceinline__ float toF(float x) { return x; }
__device__ __forceinline__ void storeT(bf16* p, float v)  { *p = __float2bfloat16(v); }
__device__ __forceinline__ void storeT(float* p, float v) { *p = v; }

template <typename T> struct dflag;                  // 1 = data is bf16
template <> struct dflag<bf16>  { static constexpr int v = 1; };
template <> struct dflag<float> { static constexpr int v = 0; };

// ---- generic zero fill (runs once, dtype-independent) ---------------------
__global__ __launch_bounds__(256) void zero_fill(float* __restrict__ p, int n) {
    int i = blockIdx.x * 256 + threadIdx.x;
    if (i < n) p[i] = 0.f;
}

// ---- dtype detector (parallel): even-index uint16s are garbage iff fp32 ---
__global__ __launch_bounds__(256) void detect_dtype(const unsigned short* __restrict__ Vraw,
                                                    int* __restrict__ flag) {
    __shared__ int cnt[256];
    const int t = threadIdx.x;
    int weird = 0;
    #pragma unroll
    for (int j = 0; j < 8; ++j) {
        unsigned short h = Vraw[2 * (t * 8 + j)];     // even bf16 slots
        int e = (h >> 7) & 0xFF;
        bool w = (e >= 127 + 21) || (e != 0 && e <= 127 - 21) ||
                 (e == 0 && (h & 0x7F));
        weird += w ? 1 : 0;
    }
    cnt[t] = weird;
    __syncthreads();
    #pragma unroll
    for (int s = 128; s > 0; s >>= 1) {
        if (t < s) cnt[t] += cnt[t + s];
        __syncthreads();
    }
    if (t == 0) *flag = (cnt[0] < 512) ? 1 : 0;       // bf16 ~0, fp32 ~1700
}

// ---- fold Wo into Wcum (chunk-prefix) and WoSum (chunk-total) -------------
template <typename T>
__global__ __launch_bounds__(256) void fold_wo(const T* __restrict__ Wo,
                                               float* __restrict__ Wcum,
                                               float* __restrict__ WoSum,
                                               const int* __restrict__ flag) {
    if (*flag != dflag<T>::v) return;
    int idx = blockIdx.x * 256 + threadIdx.x;         // 65536 threads
    int dh = idx >> 10, n = idx & 1023;
    float acc = 0.f;
    #pragma unroll
    for (int q = 0; q < 16; ++q) {
        int row = q * 64 + dh;
        Wcum[(size_t)row * 1024 + n] = acc;
        acc += toF(Wo[(size_t)row * 1024 + n]);
    }
    WoSum[(size_t)dh * 1024 + n] = acc;
}

// ---- fold Wv / bv over their 16 column chunks -----------------------------
template <typename T>
__global__ __launch_bounds__(256) void fold_wv(const T* __restrict__ Wv,
                                               const T* __restrict__ bv,
                                               float* __restrict__ WvFold,
                                               float* __restrict__ bvFold,
                                               const int* __restrict__ flag) {
    if (*flag != dflag<T>::v) return;
    int idx = blockIdx.x * 256 + threadIdx.x;         // 65536 threads
    int k = idx >> 6, dh = idx & 63;
    float acc = 0.f;
    #pragma unroll
    for (int q = 0; q < 16; ++q)
        acc += toF(Wv[(size_t)k * 1024 + q * 64 + dh]);
    WvFold[(size_t)k * 64 + dh] = acc;
    if (idx < 64) {
        float b = 0.f;
        #pragma unroll
        for (int q = 0; q < 16; ++q) b += toF(bv[q * 64 + idx]);
        bvFold[idx] = b;
    }
}

// ---- bvc[n] = sum_d bv[d]*Wcum[d,n], split-D atomics into bbig[0..1023] ---
template <typename T>
__global__ __launch_bounds__(256) void compute_bvc(const T* __restrict__ bv,
                                                   const float* __restrict__ Wcum,
                                                   float* __restrict__ bbig,
                                                   const int* __restrict__ flag) {
    if (*flag != dflag<T>::v) return;
    const int n = blockIdx.x * 256 + threadIdx.x;     // grid (4, 8)
    const int d0 = blockIdx.y * 128;
    float acc = 0.f;
    #pragma unroll 4
    for (int d = d0; d < d0 + 128; ++d)
        acc += toF(bv[d]) * Wcum[(size_t)d * 1024 + n];
    atomicAdd(&bbig[n], acc);
}

// ---- b2[n] = sum_dh bvFold[dh]*WoSum[dh,n] -> bbig[1024+n] ----------------
__global__ __launch_bounds__(256) void compute_b2(const float* __restrict__ bvFold,
                                                  const float* __restrict__ WoSum,
                                                  float* __restrict__ bbig,
                                                  const int* __restrict__ flag,
                                                  int want) {
    if (*flag != want) return;
    const int n = blockIdx.x * 256 + threadIdx.x;     // 4 blocks
    float acc = 0.f;
    #pragma unroll 8
    for (int dh = 0; dh < 64; ++dh)
        acc += bvFold[dh] * WoSum[(size_t)dh * 1024 + n];
    bbig[1024 + n] = acc;
}

// ---- C[M,N] = A[M,K] @ B[K,N] (+bias) -- 128x128 tile, BK=16, 256 thr -----
// 8x8 microtile split as 2x(4+4); all LDS access via b128, <=2-way conflicts.
// kslices>1: K split along gridDim.z, atomicAdd into pre-zeroed C (no bias).
template <typename TA>
__device__ __forceinline__ void load8(const TA* p, float* v);
template <>
__device__ __forceinline__ void load8<float>(const float* p, float* v) {
    float4 a = *(const float4*)p, b = *(const float4*)(p + 4);
    v[0]=a.x; v[1]=a.y; v[2]=a.z; v[3]=a.w;
    v[4]=b.x; v[5]=b.y; v[6]=b.z; v[7]=b.w;
}
template <>
__device__ __forceinline__ void load8<bf16>(const bf16* p, float* v) {
    ushort8 h = *(const ushort8*)p;                   // one 16B load
    #pragma unroll
    for (int i = 0; i < 8; ++i)
        v[i] = __uint_as_float(((unsigned)h[i]) << 16);
}

template <typename TA>
__global__ __launch_bounds__(256, 2)
void gemm128(const TA* __restrict__ A, int lda,
             const float* __restrict__ B, int ldb,
             const float* __restrict__ bias,
             float* __restrict__ C, int ldc,
             int K, int kslices,
             const int* __restrict__ flag, int want) {
    if (*flag != want) return;
    __shared__ __align__(16) float As[16][128];       // [k][m]
    __shared__ __align__(16) float Bs[16][128];       // [k][n]

    const int tid = threadIdx.x;
    const int tx = tid & 15;                          // n-group 0..15
    const int ty = tid >> 4;                          // m-group 0..15

    // XCD-aware swizzle over (x,y): contiguous tile range per XCD
    const int gx = gridDim.x;
    int lin = blockIdx.y * gx + blockIdx.x;
    const int nwg = gx * gridDim.y;
    if ((nwg & 7) == 0) {
        const int per = nwg >> 3;
        lin = (lin & 7) * per + (lin >> 3);
    }
    const int m0 = (lin / gx) * 128;
    const int n0 = (lin % gx) * 128;

    const int ksz  = K / kslices;
    const int kbeg = blockIdx.z * ksz;
    const int kend = kbeg + ksz;

    // staging roles
    const int arow  = tid >> 1;                       // 0..127
    const int ahalf = (tid & 1) * 8;                  // k-half 0/8
    const int brow  = tid >> 4;                       // 0..15
    const int bcol  = (tid & 15) * 4;                 // 0..60

    float acc[8][8] = {};                             // [m-frag][n-frag]

    for (int k0 = kbeg; k0 < kend; k0 += 16) {
        // A tile 128x16 -> As[k][m] (transposed in LDS)
        {
            const TA* ap = A + (size_t)(m0 + arow) * lda + (k0 + ahalf);
            float av[8];
            load8<TA>(ap, av);
            #pragma unroll
            for (int i = 0; i < 8; ++i) As[ahalf + i][arow] = av[i];
        }
        // B tile 16x128 -> Bs[k][n], two 64-wide halves (2-way max)
        {
            const float* bp = B + (size_t)(k0 + brow) * ldb + n0 + bcol;
            float4 b0 = *(const float4*)bp;
            float4 b1 = *(const float4*)(bp + 64);
            *(float4*)&Bs[brow][bcol]      = b0;
            *(float4*)&Bs[brow][bcol + 64] = b1;
        }
        __syncthreads();
        #pragma unroll
        for (int kk = 0; kk < 16; ++kk) {
            float4 aL = *(const float4*)&As[kk][ty * 4];
            float4 aH = *(const float4*)&As[kk][64 + ty * 4];
            float4 bL = *(const float4*)&Bs[kk][tx * 4];
            float4 bH = *(const float4*)&Bs[kk][64 + tx * 4];
            float a[8] = {aL.x, aL.y, aL.z, aL.w, aH.x, aH.y, aH.z, aH.w};
            float b[8] = {bL.x, bL.y, bL.z, bL.w, bH.x, bH.y, bH.z, bH.w};
            #pragma unroll
            for (int i = 0; i < 8; ++i)
                #pragma unroll
                for (int j = 0; j < 8; ++j)
                    acc[i][j] += a[i] * b[j];
        }
        __syncthreads();
    }

    // epilogue
    float bb[8];
    #pragma unroll
    for (int j = 0; j < 4; ++j) {
        bb[j]     = bias ? bias[n0 + tx * 4 + j]      : 0.f;
        bb[4 + j] = bias ? bias[n0 + 64 + tx * 4 + j] : 0.f;
    }
    #pragma unroll
    for (int ih = 0; ih < 2; ++ih)
        #pragma unroll
        for (int ii = 0; ii < 4; ++ii) {
            const int m = m0 + ih * 64 + ty * 4 + ii;
            float* crow = C + (size_t)m * ldc + n0;
            #pragma unroll
            for (int jh = 0; jh < 2; ++jh) {
                const int nc = jh * 64 + tx * 4;
                if (kslices > 1) {
                    #pragma unroll
                    for (int j = 0; j < 4; ++j)
                        atomicAdd(&crow[nc + j], acc[ih * 4 + ii][jh * 4 + j]);
                } else {
                    float4 v;
                    v.x = acc[ih * 4 + ii][jh * 4 + 0] + bb[jh * 4 + 0];
                    v.y = acc[ih * 4 + ii][jh * 4 + 1] + bb[jh * 4 + 1];
                    v.z = acc[ih * 4 + ii][jh * 4 + 2] + bb[jh * 4 + 2];
                    v.w = acc[ih * 4 + ii][jh * 4 + 3] + bb[jh * 4 + 3];
                    *(float4*)&crow[nc] = v;
                }
            }
        }
}

// ---- suffix-scan epilogue: out = bo[n] - 1e9*(suffix(G) + u) --------------
// ubig row layout: cols 0..1023 = u, 1024..2047 = G (adjacent loads).
template <typename T>
__global__ __launch_bounds__(256) void scan_epilogue(const float* __restrict__ ubig,
                                                     const T* __restrict__ bo,
                                                     T* __restrict__ out,
                                                     const int* __restrict__ flag) {
    if (*flag != dflag<T>::v) return;
    const int n = blockIdx.x * 256 + threadIdx.x;     // grid (4,16,2)
    const int h = blockIdx.y, b = blockIdx.z;
    const size_t rowbase = (size_t)b * 2048 + (size_t)h * 128;
    const float bias = toF(bo[n]);
    float acc = 0.f;                                  // sum_{r>t} G
    #pragma unroll 4
    for (int t = 127; t >= 0; --t) {
        const size_t row = rowbase + t;
        const float uval = ubig[row * 2048 + n];
        const float gval = ubig[row * 2048 + 1024 + n];
        storeT(&out[row * 1024 + n], bias - 1e9f * (acc + uval));
        acc += gval;
    }
}

template <typename T>
static void launch_pipeline(void* const* d_in, void* d_out, float* ws,
                            const int* flag, hipStream_t stream) {
    const T* V  = (const T*)d_in[2];
    const T* Wv = (const T*)d_in[8];
    const T* bv = (const T*)d_in[9];
    const T* Wo = (const T*)d_in[10];
    const T* bo = (const T*)d_in[11];
    T* out = (T*)d_out;
    constexpr int want = dflag<T>::v;

    float* Wcum  = ws + OFF_WCUM;
    float* Wbig  = ws + OFF_WBIG;
    float* ubig  = ws + OFF_UBIG;
    float* WoSum = ws + OFF_WOSUM;
    float* WvF   = ws + OFF_WVF;
    float* bbig  = ws + OFF_BBIG;
    float* bvF   = ws + OFF_BVF;

    fold_wo<T><<<256, 256, 0, stream>>>(Wo, Wcum, WoSum, flag);
    fold_wv<T><<<256, 256, 0, stream>>>(Wv, bv, WvF, bvF, flag);
    compute_bvc<T><<<dim3(4, 8), 256, 0, stream>>>(bv, Wcum, bbig, flag);
    compute_b2<<<4, 256, 0, stream>>>(bvF, WoSum, bbig, flag, want);
    // Wvc = Wv @ Wcum -> Wbig cols 0..1023   [1024,1024,K=1024] split-K=4
    gemm128<T><<<dim3(8, 8, 4), 256, 0, stream>>>(Wv, 1024, Wcum, 1024,
                                                  nullptr, Wbig, 2048,
                                                  1024, 4, flag, want);
    // W2 = WvFold @ WoSum -> Wbig cols 1024..2047   [1024,1024,K=64]
    gemm128<float><<<dim3(8, 8), 256, 0, stream>>>(WvF, 64, WoSum, 1024,
                                                   nullptr, Wbig + 1024, 2048,
                                                   64, 1, flag, want);
    // ubig = V @ Wbig + bbig   [4096,2048,K=1024], 512 blocks = 2/CU exact
    gemm128<T><<<dim3(16, 32), 256, 0, stream>>>(V, 1024, Wbig, 2048,
                                                 bbig, ubig, 2048,
                                                 1024, 1, flag, want);
    scan_epilogue<T><<<dim3(4, 16, 2), 256, 0, stream>>>(ubig, bo, out, flag);
}

extern "C" void kernel_launch(void* const* d_in, const int* in_sizes, int n_in,
                              void* d_out, int out_size, void* d_ws, size_t ws_size,
                              hipStream_t stream) {
    float* ws = (float*)d_ws;
    int* flag = (int*)(ws + OFF_FLAG);

    // zero the atomic-accumulated regions once (dtype-independent)
    zero_fill<<<8192, 256, 0, stream>>>(ws + OFF_WBIG, 2097152);
    zero_fill<<<8, 256, 0, stream>>>(ws + OFF_BBIG, 2048);
    detect_dtype<<<1, 256, 0, stream>>>((const unsigned short*)d_in[2], flag);
    launch_pipeline<bf16>(d_in, d_out, ws, flag, stream);   // runs iff flag==1
    launch_pipeline<float>(d_in, d_out, ws, flag, stream);  // runs iff flag==0
}